// Round 3
// baseline (323.946 us; speedup 1.0000x reference)
//
#include <hip/hip_runtime.h>
#include <cstddef>

static constexpr int CB = 64;    // batch
static constexpr int CN = 512;   // nodes
static constexpr int CD = 256;   // node model dim
static constexpr int CE = 128;   // edge model dim
static constexpr int CIT = 20;   // sinkhorn iterations

typedef _Float16 half_t;
typedef __attribute__((ext_vector_type(8))) _Float16 v8h;
typedef __attribute__((ext_vector_type(4))) _Float16 v4h;
typedef __attribute__((ext_vector_type(4))) float v4f;

// ---------------------------------------------------------------------------
// Dual-channel fence-free sentinel exchange (R2-validated protocol + new L2
// side channel). Producers publish the 16B payload TWICE:
//   sc0       -> shared XCD L2 (visible to same-XCD peers in ~0.2 µs)
//   sc0 sc1   -> LLC/memory   (visible to ANY peer — the validated safe path)
// Consumers poll BOTH slots; accept whichever granule flips all-positive
// first. If the 4 slab-blocks of a batch don't share an XCD, the L2 copy is
// simply never seen and behavior degrades to exactly the R2 protocol —
// deadlock-free, no placement assumption (G16-safe).
// No fences anywhere (R1 showed release/acquire => buffer_wbl2/inv storms).
// ---------------------------------------------------------------------------
__device__ __forceinline__ void store_dual(v4f* l2p, v4f* llcp, v4f v) {
  asm volatile("global_store_dwordx4 %0, %2, off sc0\n\t"
               "global_store_dwordx4 %1, %2, off sc0 sc1"
               :: "v"(l2p), "v"(llcp), "v"(v) : "memory");
}
__device__ __forceinline__ void poll6(const v4f* a0, const v4f* a1,
                                      const v4f* a2, const v4f* c0,
                                      const v4f* c1, const v4f* c2,
                                      v4f& x0, v4f& x1, v4f& x2,
                                      v4f& y0, v4f& y1, v4f& y2) {
  asm volatile("global_load_dwordx4 %0, %6, off sc0\n\t"
               "global_load_dwordx4 %1, %7, off sc0\n\t"
               "global_load_dwordx4 %2, %8, off sc0\n\t"
               "global_load_dwordx4 %3, %9, off sc0 sc1\n\t"
               "global_load_dwordx4 %4, %10, off sc0 sc1\n\t"
               "global_load_dwordx4 %5, %11, off sc0 sc1\n\t"
               "s_waitcnt vmcnt(0)"
               : "=&v"(x0), "=&v"(x1), "=&v"(x2),
                 "=&v"(y0), "=&v"(y1), "=&v"(y2)
               : "v"(a0), "v"(a1), "v"(a2), "v"(c0), "v"(c1), "v"(c2)
               : "memory");
}
__device__ __forceinline__ bool allpos(v4f v) {
  return v[0] > 0.0f && v[1] > 0.0f && v[2] > 0.0f && v[3] > 0.0f;
}

// ---------------------------------------------------------------------------
// k0: block 0 = mask layout detect; block 1 = idle; blocks 2..9 = W_a -> fp16
// B-fragments (w_aff folded); 10..17 = W_b; blocks >= 18 clear BOTH dataflow
// channel regions to -1.0f (21 MB). flag: 0=int32, 1=uint8, 2=f32, 3=int64
// ---------------------------------------------------------------------------
__global__ __launch_bounds__(512) void k0_init(
    const void* __restrict__ mask, int* __restrict__ flag,
    const float* __restrict__ W_a, const float* __restrict__ W_b,
    const float* __restrict__ w_aff,
    half_t* __restrict__ WaF, half_t* __restrict__ WbF,
    float4* __restrict__ clearp, int nclear4) {
  const int tid = threadIdx.x;
  const int blk = blockIdx.x;
  if (blk == 1) return;
  if (blk >= 18) {
    const int idx = (blk - 18) * 512 + tid;
    if (idx < nclear4)
      clearp[idx] = make_float4(-1.0f, -1.0f, -1.0f, -1.0f);
    return;
  }
  if (blk >= 2) {
    const bool is_a = (blk < 10);
    const float* W = is_a ? W_a : W_b;
    half_t* WF = is_a ? WaF : WbF;
    const int e = (blk - (is_a ? 2 : 10)) * 512 + tid;   // 0..4095
    const int fB = e >> 6, lane = e & 63;
    const int nn = fB >> 3, kf = fB & 7;
    const int col = nn * 16 + (lane & 15);
    const int q = lane >> 4;
    const float scale = is_a ? w_aff[col] : 1.0f;
    v8h hv;
#pragma unroll
    for (int j = 0; j < 8; ++j) {
      const int k = kf * 32 + q * 8 + j;
      hv[j] = (half_t)(W[(size_t)k * CE + col] * scale);
    }
    *(v8h*)&WF[(size_t)e * 8] = hv;
    return;
  }
  // blk == 0: mask dtype detection over first 32768 bytes
  __shared__ int cnt[5];
  if (tid < 5) cnt[tid] = 0;
  __syncthreads();
  const unsigned char* p = (const unsigned char*)mask;
  int l0 = 0, l1 = 0, l2 = 0, l3 = 0, l4 = 0;
  const int base = tid * 64;
  for (int k = 0; k < 64; ++k) {
    const int off = base + k;
    if (p[off]) {
      const int m4 = off & 3;
      if (m4 == 1) l1++;
      else if (m4 == 2) l2++;
      else if (m4 == 3) l3++;
      else if ((off & 7) == 4) l4++;
      else l0++;
    }
  }
  if (l0) atomicAdd(&cnt[0], 1);
  if (l1) atomicAdd(&cnt[1], 1);
  if (l2) atomicAdd(&cnt[2], 1);
  if (l3) atomicAdd(&cnt[3], 1);
  if (l4) atomicAdd(&cnt[4], 1);
  __syncthreads();
  if (tid == 0) {
    int f;
    if (cnt[1]) f = 1;
    else if (cnt[2] || cnt[3]) f = 2;
    else if (cnt[4]) f = 0;
    else if (cnt[0]) f = 3;
    else f = 1;
    *flag = f;
  }
}

// ---------------------------------------------------------------------------
// prep_both (validated R7/R8): ONE dispatch for both prep GEMMs. Blocks
// 0..511 = A-path (x = out_emb + pos, W = WaF w/ w_aff folded); 512..1023 =
// B-path (x = mask ? pad : in_emb, W = WbF). out fp16 row-major, K=256.
// ---------------------------------------------------------------------------
__global__ __launch_bounds__(256) void prep_both(
    const float* __restrict__ out_emb, const float* __restrict__ pos,
    const float* __restrict__ in_emb, const float* __restrict__ pad,
    const void* __restrict__ maskp, const int* __restrict__ flagp,
    const half_t* __restrict__ WaF, const half_t* __restrict__ WbF,
    half_t* __restrict__ A_h, half_t* __restrict__ Bm_h) {
  __shared__ half_t Xs[64][264];   // 33.8 KB
  const int tid = threadIdx.x;
  const int wv = tid >> 6, ln = tid & 63;
  const bool isA = blockIdx.x < 512;
  const int row0 = (isA ? blockIdx.x : blockIdx.x - 512) * 64;
  const float* X = isA ? out_emb : in_emb;
  const float* extra = isA ? pos : pad;
  const half_t* Wfrag = isA ? WaF : WbF;
  half_t* out = isA ? A_h : Bm_h;
  const int flag = isA ? 0 : *flagp;

#pragma unroll 4
  for (int it = 0; it < 16; ++it) {
    const int r = it * 4 + wv;
    const int row = row0 + r;
    const int c = ln * 4;
    float4 x4;
    if (isA) {
      x4 = *(const float4*)&X[(size_t)row * CD + c];
      const int i = row & (CN - 1);
      const float4 p4 = *(const float4*)&extra[(size_t)i * CD + c];
      x4.x += p4.x; x4.y += p4.y; x4.z += p4.z; x4.w += p4.w;
    } else {
      bool m;
      if (flag == 1)      m = ((const unsigned char*)maskp)[row] != 0;
      else if (flag == 2) m = ((const float*)maskp)[row] != 0.0f;
      else if (flag == 3) m = ((const long long*)maskp)[row] != 0;
      else                m = ((const int*)maskp)[row] != 0;
      if (m) x4 = *(const float4*)&extra[c];
      else   x4 = *(const float4*)&X[(size_t)row * CD + c];
    }
    v4h hv;
    hv[0] = (half_t)x4.x; hv[1] = (half_t)x4.y;
    hv[2] = (half_t)x4.z; hv[3] = (half_t)x4.w;
    *(v4h*)&Xs[r][c] = hv;
  }
  __syncthreads();

  const int q = ln >> 4, l = ln & 15;
  v8h af[8];
#pragma unroll
  for (int kf = 0; kf < 8; ++kf)
    af[kf] = *(v8h*)&Xs[wv * 16 + l][kf * 32 + q * 8];
  v4f acc[8] = {};
#pragma unroll
  for (int nn = 0; nn < 8; ++nn) {
    v8h bf[8];
#pragma unroll
    for (int kf = 0; kf < 8; ++kf)
      bf[kf] = *(const v8h*)&Wfrag[(size_t)((nn * 8 + kf) * 64 + ln) * 8];
#pragma unroll
    for (int kf = 0; kf < 8; ++kf)
      acc[nn] = __builtin_amdgcn_mfma_f32_16x16x32_f16(af[kf], bf[kf], acc[nn], 0, 0, 0);
  }
#pragma unroll
  for (int nn = 0; nn < 8; ++nn)
#pragma unroll
    for (int g = 0; g < 4; ++g) {
      const int row = row0 + wv * 16 + q * 4 + g;
      out[(size_t)row * CE + nn * 16 + l] = (half_t)acc[nn][g];
    }
}

// ---------------------------------------------------------------------------
// fused_reg: block = (batch b, 128-row slab), 512 thr = 8 waves, grid 256.
// E slab in registers TWICE as fp16 (eh = C-layout, ehT = transposed twin).
// Packed Sinkhorn passes (validated R1/R2 math). Exchange = dual-channel
// sentinel (L2 fast path + LLC safe path, see helpers above). w1/w2 live in
// ONE shared array with the w2 half at a +16-bank offset (kills the 5.3M
// 2-way bank-alias conflicts from R1/R2's twin 1KB arrays).
// ---------------------------------------------------------------------------
__global__ __launch_bounds__(512, 2) void fused_reg(
    const half_t* __restrict__ A_h, const half_t* __restrict__ B_h,
    const float* __restrict__ baff, float* __restrict__ P,
    float* __restrict__ partInit, float* __restrict__ partIter,
    float* __restrict__ partInitL2, float* __restrict__ partIterL2) {
  __shared__ float comb2[8][512][2];           // 32 KB, [wave][col][s1|s2]
  __shared__ __align__(16) float2 w12[512];    // {0.5*v*csinv, v} (finalize)
  __shared__ __align__(16) float QsL[512];     // per-col publish staging
  __shared__ __align__(16) v4f csinv4[128];    // 1/colsum, 4 cols per slot
  __shared__ __align__(16) half_t wAll[1056];  // w1 @0, w2 @544 (+16 banks)

  const int tid = threadIdx.x;
  const int wv = tid >> 6, ln = tid & 63;
  const int q = ln >> 4, l = ln & 15;
  const int b = blockIdx.x & 63;
  const int slab = blockIdx.x >> 6;
  const int i0 = slab * 128;
  const float bbs = *baff - 2.7725887f;   // fold 2^-4 scale into exp

  int rs3[3];   // the 3 remote slabs (static-indexed only)
  {
    int k = 0;
#pragma unroll
    for (int sl = 0; sl < 4; ++sl)
      if (sl != slab) rs3[k++] = sl;
  }

  // ---- GEMM: E and E^T tiles, fp16 MFMA, K=128 ----
  v8h af[4];
  {
    const half_t* Arow = &A_h[((size_t)b * CN + i0 + wv * 16 + l) * CE];
#pragma unroll
    for (int ki = 0; ki < 4; ++ki)
      af[ki] = *(const v8h*)&Arow[ki * 32 + q * 8];
  }
  v4h eh[32];    // E[row = wv*16 + q*4+g][col = ct*16 + l]
  v4h ehT[32];   // E[row = wv*16 + l][col = ct*16 + q*4+g]
  const half_t* Bbase = &B_h[(size_t)b * CN * CE];
#pragma unroll
  for (int ct = 0; ct < 32; ++ct) {
    v8h bf[4];
    const half_t* Brow = &Bbase[(size_t)(ct * 16 + l) * CE];
#pragma unroll
    for (int ki = 0; ki < 4; ++ki)
      bf[ki] = *(const v8h*)&Brow[ki * 32 + q * 8];
    v4f acc = {}, accT = {};
#pragma unroll
    for (int ki = 0; ki < 4; ++ki) {
      acc  = __builtin_amdgcn_mfma_f32_16x16x32_f16(af[ki], bf[ki], acc,  0, 0, 0);
      accT = __builtin_amdgcn_mfma_f32_16x16x32_f16(bf[ki], af[ki], accT, 0, 0, 0);
    }
#pragma unroll
    for (int g = 0; g < 4; ++g) {
      eh[ct][g]  = (half_t)__expf(acc[g]  + bbs);
      ehT[ct][g] = (half_t)__expf(accT[g] + bbs);
    }
  }

  // ---- init sums via MFMA (ones fragment) ----
  v4h ones;
  ones[0] = (half_t)1.0f; ones[1] = (half_t)1.0f;
  ones[2] = (half_t)1.0f; ones[3] = (half_t)1.0f;
  v4f rowacc0 = {}, rowacc1 = {};
#pragma unroll
  for (int ct = 0; ct < 32; ct += 2) {
    const v4f c0 = __builtin_amdgcn_mfma_f32_16x16x16f16(ones, eh[ct], (v4f){}, 0, 0, 0);
    const v4f c1 = __builtin_amdgcn_mfma_f32_16x16x16f16(ones, eh[ct + 1], (v4f){}, 0, 0, 0);
    if (ln < 16) {
      comb2[wv][ct * 16 + ln][0] = c0[0];
      comb2[wv][(ct + 1) * 16 + ln][0] = c1[0];
    }
    rowacc0 = __builtin_amdgcn_mfma_f32_16x16x16f16(ones, ehT[ct],     rowacc0, 0, 0, 0);
    rowacc1 = __builtin_amdgcn_mfma_f32_16x16x16f16(ones, ehT[ct + 1], rowacc1, 0, 0, 0);
  }
  const float rowtot = rowacc0[0] + rowacc1[0];
  float rv[4];   // 1/rowsum for this lane's 4 rows (q*4+g)
#pragma unroll
  for (int g = 0; g < 4; ++g)
    rv[g] = 1.0f / __shfl(rowtot, q * 4 + g);
  __syncthreads();

  // ---- init exchange: dual-channel sentinel, 16B ops on 128 threads ----
  {
    float S = 0.0f;
#pragma unroll
    for (int w = 0; w < 8; ++w) S += comb2[w][tid][0];
    QsL[tid] = S;                 // colsum staging (strictly positive)
  }
  __syncthreads();
  if (tid < 128) {
    const v4f s4 = *(const v4f*)&QsL[tid * 4];
    v4f* piL = (v4f*)partInitL2 + (size_t)b * 4 * 128;
    v4f* piC = (v4f*)partInit   + (size_t)b * 4 * 128;
    store_dual(&piL[slab * 128 + tid], &piC[slab * 128 + tid], s4);
    const v4f* a0 = &piL[rs3[0] * 128 + tid];
    const v4f* a1 = &piL[rs3[1] * 128 + tid];
    const v4f* a2 = &piL[rs3[2] * 128 + tid];
    const v4f* c0 = &piC[rs3[0] * 128 + tid];
    const v4f* c1 = &piC[rs3[1] * 128 + tid];
    const v4f* c2 = &piC[rs3[2] * 128 + tid];
    v4f s0, s1, s2;
    bool g0 = false, g1 = false, g2 = false;
    while (true) {
      v4f x0, x1, x2, y0, y1, y2;
      poll6(a0, a1, a2, c0, c1, c2, x0, x1, x2, y0, y1, y2);
      if (!g0) { if (allpos(x0)) { s0 = x0; g0 = true; } else if (allpos(y0)) { s0 = y0; g0 = true; } }
      if (!g1) { if (allpos(x1)) { s1 = x1; g1 = true; } else if (allpos(y1)) { s1 = y1; g1 = true; } }
      if (!g2) { if (allpos(x2)) { s2 = x2; g2 = true; } else if (allpos(y2)) { s2 = y2; g2 = true; } }
      if (g0 && g1 && g2) break;
      __builtin_amdgcn_s_sleep(1);
    }
    const v4f T = s4 + s0 + s1 + s2;
    v4f ci;
    v4h w1v, w2v;
#pragma unroll
    for (int j = 0; j < 4; ++j) {
      ci[j] = 1.0f / T[j];
      w1v[j] = (half_t)(0.5f * ci[j]);
      w2v[j] = (half_t)1.0f;
    }
    csinv4[tid] = ci;
    *(v4h*)&wAll[tid * 4] = w1v;
    *(v4h*)&wAll[544 + tid * 4] = w2v;
  }
  __syncthreads();
  const float ci0 = ((const float*)csinv4)[tid];   // 1/colsum for column tid

  // ---- 20 sinkhorn iterations (packed MFMA passes) ----
  const half_t* wbase = (l == 1) ? (wAll + 544) : wAll;   // row0=w1, row1=w2
  float u_[4], uri[4];
  for (int t = 0; t < CIT; ++t) {
    __syncthreads();   // wAll ready
    // pass 1: row dots via E^T tiles; ONE mfma per ct (rows 0/1 = w1/w2)
    v4f Pe = {}, Po = {};
#pragma unroll
    for (int ct = 0; ct < 32; ct += 2) {
      const v4h wf0 = *(const v4h*)&wbase[ct * 16 + q * 4];
      const v4h wf1 = *(const v4h*)&wbase[(ct + 1) * 16 + q * 4];
      Pe = __builtin_amdgcn_mfma_f32_16x16x16f16(wf0, ehT[ct],     Pe, 0, 0, 0);
      Po = __builtin_amdgcn_mfma_f32_16x16x16f16(wf1, ehT[ct + 1], Po, 0, 0, 0);
    }
    const float Prow1 = Pe[0] + Po[0];   // w1-weighted row dot (C row 0)
    const float Prow2 = Pe[1] + Po[1];   // w2-weighted row dot (C row 1)
    // redistribute p[row l&15] -> this lane's rows q*4+g; compute u
    v4h u_h, uri_h;
#pragma unroll
    for (int g = 0; g < 4; ++g) {
      const float p1 = __shfl(Prow1, q * 4 + g);
      const float p2 = __shfl(Prow2, q * 4 + g);
      u_[g] = 1.0f / (p1 + 0.5f * rv[g] * p2);
      uri[g] = u_[g] * rv[g];
      u_h[g] = (half_t)u_[g];
      uri_h[g] = (half_t)uri[g];
    }
    // pass 2: column partials via E tiles; rows 0/1 of A = u/uri packed
    const v4h a2 = (l == 1) ? uri_h : u_h;
#pragma unroll
    for (int ct = 0; ct < 32; ++ct) {
      const v4f s = __builtin_amdgcn_mfma_f32_16x16x16f16(a2, eh[ct], (v4f){}, 0, 0, 0);
      if (ln < 16)
        *(float2*)&comb2[wv][ct * 16 + ln][0] = make_float2(s[0], s[1]);
    }
    __syncthreads();
    // cross-wave reduce (all 512 threads) + stage Q = 0.5*(ci*S1 + S2)
    {
      float S1 = 0.0f, S2 = 0.0f;
#pragma unroll
      for (int w = 0; w < 8; ++w) {
        const float2 c2v = *(const float2*)&comb2[w][tid][0];
        S1 += c2v.x;
        S2 += c2v.y;
      }
      QsL[tid] = 0.5f * fmaf(ci0, S1, S2);   // strictly positive
    }
    __syncthreads();
    // 128-thread dual-channel sentinel exchange + w update
    if (tid < 128) {
      const v4f Q4 = *(const v4f*)&QsL[tid * 4];
      v4f* prL = (v4f*)partIterL2 + (((size_t)t * 64 + b) * 4) * 128;
      v4f* prC = (v4f*)partIter   + (((size_t)t * 64 + b) * 4) * 128;
      store_dual(&prL[slab * 128 + tid], &prC[slab * 128 + tid], Q4);
      const v4f* a0 = &prL[rs3[0] * 128 + tid];
      const v4f* a1 = &prL[rs3[1] * 128 + tid];
      const v4f* a2p = &prL[rs3[2] * 128 + tid];
      const v4f* c0 = &prC[rs3[0] * 128 + tid];
      const v4f* c1 = &prC[rs3[1] * 128 + tid];
      const v4f* c2 = &prC[rs3[2] * 128 + tid];
      v4f s0, s1, s2;
      bool g0 = false, g1 = false, g2 = false;
      while (true) {
        v4f x0, x1, x2, y0, y1, y2;
        poll6(a0, a1, a2p, c0, c1, c2, x0, x1, x2, y0, y1, y2);
        if (!g0) { if (allpos(x0)) { s0 = x0; g0 = true; } else if (allpos(y0)) { s0 = y0; g0 = true; } }
        if (!g1) { if (allpos(x1)) { s1 = x1; g1 = true; } else if (allpos(y1)) { s1 = y1; g1 = true; } }
        if (!g2) { if (allpos(x2)) { s2 = x2; g2 = true; } else if (allpos(y2)) { s2 = y2; g2 = true; } }
        if (g0 && g1 && g2) break;
        __builtin_amdgcn_s_sleep(1);
      }
      const v4f tot = Q4 + s0 + s1 + s2;
      const v4f ci = csinv4[tid];
      v4h w1v, w2v;
#pragma unroll
      for (int j = 0; j < 4; ++j) {
        const float vv = 1.0f / tot[j];
        w1v[j] = (half_t)(0.5f * vv * ci[j]);
        w2v[j] = (half_t)vv;
        if (t == CIT - 1)
          w12[tid * 4 + j] = make_float2(0.5f * vv * ci[j], vv);
      }
      *(v4h*)&wAll[tid * 4] = w1v;
      *(v4h*)&wAll[544 + tid * 4] = w2v;
    }
  }

  // ---- finalize: P = E * u_i * v_j * (0.5*csinv_j + 0.5*rinv_i) ----
  __syncthreads();
  float* Pb = &P[((size_t)b * CN + i0 + wv * 16 + q * 4) * CN];
#pragma unroll
  for (int ct = 0; ct < 32; ++ct) {
    const float2 w = w12[ct * 16 + l];
    const float c1 = w.x;
    const float c2 = 0.5f * w.y;
#pragma unroll
    for (int g = 0; g < 4; ++g) {
      const float e = (float)eh[ct][g];
      Pb[(size_t)g * CN + ct * 16 + l] = e * fmaf(u_[g], c1, uri[g] * c2);
    }
  }
}

// ---------------------------------------------------------------------------
extern "C" void kernel_launch(void* const* d_in, const int* in_sizes, int n_in,
                              void* d_out, int out_size, void* d_ws, size_t ws_size,
                              hipStream_t stream) {
  const float* in_emb  = (const float*)d_in[0];
  const void*  mask    = d_in[1];
  const float* out_emb = (const float*)d_in[2];
  const float* pad     = (const float*)d_in[3];
  const float* pos     = (const float*)d_in[4];
  const float* W_a     = (const float*)d_in[5];
  const float* W_b     = (const float*)d_in[6];
  const float* w_aff   = (const float*)d_in[7];
  const float* b_aff   = (const float*)d_in[8];
  float* P = (float*)d_out;

  char* ws = (char*)d_ws;
  const size_t MB = 1024 * 1024;
  const size_t KB = 1024;
  half_t* A_h  = (half_t*)ws;                              // 8 MB
  half_t* Bm_h = (half_t*)(ws + 8 * MB);                   // 8 MB
  int*    flag = (int*)(ws + 16 * MB);                     // 4 B
  half_t* WaF  = (half_t*)(ws + 16 * MB + 16 * KB);        // 64 KB
  half_t* WbF  = (half_t*)(ws + 16 * MB + 80 * KB);        // 64 KB
  // dual-channel dataflow slots, contiguous for the preclear:
  float* partInit   = (float*)(ws + 16 * MB + 256 * KB);            // 512 KB (LLC)
  float* partInitL2 = (float*)(ws + 16 * MB + 768 * KB);            // 512 KB (L2)
  float* partIter   = (float*)(ws + 16 * MB + 1280 * KB);           // 10 MB (LLC)
  float* partIterL2 = (float*)(ws + 16 * MB + 1280 * KB + 10 * MB); // 10 MB (L2)

  // preclear both channels to sentinel -1: 0.5+0.5+10+10 = 21 MB
  const int nclear4 = (21 * 1024 * 1024) / 16;   // 1,376,256 float4
  const int nclrblk = (nclear4 + 511) / 512;     // 2688

  k0_init<<<dim3(18 + nclrblk), dim3(512), 0, stream>>>(
      mask, flag, W_a, W_b, w_aff, WaF, WbF, (float4*)partInit, nclear4);
  prep_both<<<dim3(1024), dim3(256), 0, stream>>>(
      out_emb, pos, in_emb, pad, mask, flag, WaF, WbF, A_h, Bm_h);
  fused_reg<<<dim3(256), dim3(512), 0, stream>>>(
      A_h, Bm_h, b_aff, P, partInit, partIter, partInitL2, partIterL2);
}